// Round 11
// baseline (204.247 us; speedup 1.0000x reference)
//
#include <hip/hip_runtime.h>
#include <hip/hip_bf16.h>
#include <hip/hip_fp16.h>
#include <cstdint>
#include <cstddef>

#define N_NODES 50000
#define N_PAD   50176    // padded rows for guard-free GEMM tiles
#define N_EDGES 800000
#define D_FEAT  128
#define HALF    64
#define HIDDEN  256
#define LABELS  40

#define NBUCK 196        // ceil(50000/256) buckets of 256 nodes (node>>8)
#define BCAP  5632       // staging cap per bucket; E[cnt]=4096, sigma~64 (24 sigma)
#define EDGES_PER_BLK 4096

#define HID_STRIDE 264   // LDS hidden-tile row stride (bf16)
#define NB_STRIDE  72    // LDS nbr-tile row stride (bf16): 144 B -> bank step 4, 2-way max (free)

typedef __attribute__((ext_vector_type(8))) short bf16x8;
typedef __attribute__((ext_vector_type(4))) float f32x4;

// Packed-weight layout offsets (in bf16 elements).
#define PK_SELF(L) ((size_t)(L) * 8192)
#define PK_NBR(L)  (24576 + (size_t)(L) * 8192)
#define PK_W1      49152
#define PK_W2      81920
#define PK_TOTAL   94208

__device__ inline uint16_t f2bf_bits(float f) {
    __hip_bfloat16 b = __float2bfloat16(f);
    uint16_t u; __builtin_memcpy(&u, &b, 2); return u;
}

__device__ inline float2 h2f(uint32_t u) {
    __half2 h; __builtin_memcpy(&h, &u, 4);
    return __half22float2(h);
}

// ---------------------------------------------------------------------------
// FUSED CSR scatter + weight pack (independent work, one launch).
// Blocks [0,196): bucket scatter (r6-proven). Blocks [196,228): pack.
// ---------------------------------------------------------------------------
__global__ __launch_bounds__(1024) void scatter_pack_kernel(
        const int* __restrict__ row, const int* __restrict__ col,
        int* __restrict__ bucket_cursor, uint32_t* __restrict__ staged,
        const float* __restrict__ selfk, const float* __restrict__ nbrk,
        const float* __restrict__ w1, const float* __restrict__ w2,
        __hip_bfloat16* __restrict__ wpack) {
    if (blockIdx.x >= 196) {
        // ---- weight pack: global pack-thread id in [0, 32768) ----
        int pgid = (blockIdx.x - 196) * 1024 + threadIdx.x;
        int m = pgid >> 12;                 // 4096 pack threads per matrix slot
        int t = pgid & 4095;
        const float* W; int K, Ncols, Npad; size_t dstoff;
        if (m < 3)      { W = selfk + (size_t)m*D_FEAT*HALF;      K=128; Ncols=64;  Npad=64;  dstoff = PK_SELF(m); }
        else if (m < 6) { W = nbrk  + (size_t)(m-3)*D_FEAT*HALF;  K=128; Ncols=64;  Npad=64;  dstoff = PK_NBR(m-3); }
        else if (m == 6){ W = w1;                                 K=128; Ncols=256; Npad=256; dstoff = PK_W1; }
        else            { W = w2;                                 K=256; Ncols=40;  Npad=48;  dstoff = PK_W2; }
        int ksteps = K / 32;
        int total  = ksteps * (Npad / 16) * 64;
        if (t >= total) return;
        int lane = t & 63;
        int rest = t >> 6;
        int ks   = rest % ksteps;
        int ns   = rest / ksteps;
        int colb = ns * 16 + (lane & 15);
        int kb   = ks * 32 + (lane >> 4) * 8;
        __hip_bfloat16* dst = wpack + dstoff + (size_t)t * 8;
#pragma unroll
        for (int j = 0; j < 8; j++) {
            float v = (colb < Ncols) ? W[(size_t)(kb + j) * Ncols + colb] : 0.f;
            dst[j] = __float2bfloat16(v);
        }
        return;
    }

    // ---- bucket scatter ----
    __shared__ int hist[NBUCK];
    __shared__ int hbase[NBUCK];
    int tid  = threadIdx.x;
    int e0   = blockIdx.x * EDGES_PER_BLK;
    int eend = e0 + EDGES_PER_BLK; if (eend > N_EDGES) eend = N_EDGES;

    for (int i = tid; i < NBUCK; i += 1024) hist[i] = 0;
    __syncthreads();

    int rr[4], cc[4]; int ne = 0;
    for (int e = e0 + tid; e < eend; e += 1024) {
        rr[ne] = row[e]; cc[ne] = col[e]; ne++;
    }
    for (int i = 0; i < ne; i++) atomicAdd(&hist[rr[i] >> 8], 1);
    __syncthreads();

    for (int i = tid; i < NBUCK; i += 1024) {
        hbase[i] = atomicAdd(&bucket_cursor[i], hist[i]);
        hist[i]  = 0;
    }
    __syncthreads();

    for (int i = 0; i < ne; i++) {
        int b   = rr[i] >> 8;
        int off = atomicAdd(&hist[b], 1);
        int pos = hbase[b] + off;
        if (pos < BCAP)
            staged[(size_t)b * BCAP + pos] =
                ((uint32_t)(rr[i] & 255) << 16) | (uint32_t)cc[i];
    }
}

// ---------------------------------------------------------------------------
// GEMM body (r6-proven arithmetic): one wave, 32 rows starting at row0.
// ---------------------------------------------------------------------------
template<bool AF32>
__device__ inline void gemm_wave_body(
        const void* __restrict__ Ain, int row0, int lane,
        const __hip_bfloat16* __restrict__ wpack_self,
        const __hip_bfloat16* __restrict__ wpack_nbr,
        const float* __restrict__ bias,
        __hip_bfloat16* __restrict__ hout, uint16_t* __restrict__ zn) {
    int lrow = lane & 15, lgrp = lane >> 4;

    const __hip_bfloat16 *hr0 = nullptr, *hr1 = nullptr;
    const float *xr0 = nullptr, *xr1 = nullptr;
    if constexpr (AF32) {
        const float* x = (const float*)Ain;
        int r0 = min(row0 + lrow, N_NODES - 1);        // clamp: x has exactly N_NODES rows
        int r1 = min(row0 + lrow + 16, N_NODES - 1);
        xr0 = x + (size_t)r0 * D_FEAT + lgrp * 8;
        xr1 = x + (size_t)r1 * D_FEAT + lgrp * 8;
    } else {
        const __hip_bfloat16* h = (const __hip_bfloat16*)Ain;
        hr0 = h + (size_t)(row0 + lrow) * D_FEAT + lgrp * 8;
        hr1 = hr0 + (size_t)16 * D_FEAT;
    }

    f32x4 accS[2][4] = {};
    f32x4 accN[2][4] = {};
#pragma unroll
    for (int ks = 0; ks < 4; ks++) {
        bf16x8 a0, a1;
        if constexpr (AF32) {
            float4 u0  = *(const float4*)(xr0 + ks * 32);
            float4 u0b = *(const float4*)(xr0 + ks * 32 + 4);
            float4 u1  = *(const float4*)(xr1 + ks * 32);
            float4 u1b = *(const float4*)(xr1 + ks * 32 + 4);
            float f0[8] = {u0.x, u0.y, u0.z, u0.w, u0b.x, u0b.y, u0b.z, u0b.w};
            float f1[8] = {u1.x, u1.y, u1.z, u1.w, u1b.x, u1b.y, u1b.z, u1b.w};
#pragma unroll
            for (int j = 0; j < 8; j++) { a0[j] = (short)f2bf_bits(f0[j]); a1[j] = (short)f2bf_bits(f1[j]); }
        } else {
            a0 = *(const bf16x8*)(hr0 + ks * 32);
            a1 = *(const bf16x8*)(hr1 + ks * 32);
        }
#pragma unroll
        for (int ns = 0; ns < 4; ns++) {
            bf16x8 bs = *(const bf16x8*)(wpack_self + ((size_t)(ns * 4 + ks) * 64 + lane) * 8);
            accS[0][ns] = __builtin_amdgcn_mfma_f32_16x16x32_bf16(a0, bs, accS[0][ns], 0, 0, 0);
            accS[1][ns] = __builtin_amdgcn_mfma_f32_16x16x32_bf16(a1, bs, accS[1][ns], 0, 0, 0);
            bf16x8 bn = *(const bf16x8*)(wpack_nbr + ((size_t)(ns * 4 + ks) * 64 + lane) * 8);
            accN[0][ns] = __builtin_amdgcn_mfma_f32_16x16x32_bf16(a0, bn, accN[0][ns], 0, 0, 0);
            accN[1][ns] = __builtin_amdgcn_mfma_f32_16x16x32_bf16(a1, bn, accN[1][ns], 0, 0, 0);
        }
    }
#pragma unroll
    for (int t = 0; t < 2; t++) {
#pragma unroll
        for (int ns = 0; ns < 4; ns++) {
            int colS = ns * 16 + lrow;
            float bvS = bias[colS];
#pragma unroll
            for (int i = 0; i < 4; i++) {
                int r = row0 + t * 16 + lgrp * 4 + i;     // < N_PAD, unguarded
                hout[(size_t)r * D_FEAT + colS] =
                    __float2bfloat16(fmaxf(accS[t][ns][i] + bvS, 0.f));
                __half hz = __float2half(accN[t][ns][i]);
                uint16_t hb; __builtin_memcpy(&hb, &hz, 2);
                zn[(size_t)r * HALF + colS] = hb;
            }
        }
    }
}

// ---------------------------------------------------------------------------
// FUSED: L0 GEMM + CSR bucket_fill in ONE launch (r10-proven).
// ---------------------------------------------------------------------------
__global__ __launch_bounds__(512, 2) void gemm0_fill_kernel(
        const float* __restrict__ x,
        const __hip_bfloat16* __restrict__ wpack_self,
        const __hip_bfloat16* __restrict__ wpack_nbr,
        const float* __restrict__ bias,
        __hip_bfloat16* __restrict__ hout, uint16_t* __restrict__ zn,
        const uint32_t* __restrict__ staged, const int* __restrict__ bucket_cursor,
        int* __restrict__ deg, int* __restrict__ rowstart,
        float* __restrict__ inv_deg, uint16_t* __restrict__ csr_col) {
    __shared__ int cnt[256];
    __shared__ int excl[256];
    __shared__ int wt[4];
    __shared__ int seg[BCAP];
    __shared__ int base_s;

    if (blockIdx.x < 196) {
        // ---- L0 GEMM: 256 rows/block ----
        int wave = threadIdx.x >> 6, lane = threadIdx.x & 63;
        int row0 = blockIdx.x * 256 + wave * 32;
        gemm_wave_body<true>((const void*)x, row0, lane,
                             wpack_self, wpack_nbr, bias, hout, zn);
        return;
    }

    // ---- bucket_fill (r6 algorithm, 512 threads) ----
    int b   = blockIdx.x - 196;
    int tid = threadIdx.x;

    if (tid < 64) {                      // wave 0: gbase = sum cursor[i<b]
        int partial = 0;
        for (int i = tid; i < b; i += 64) partial += bucket_cursor[i];
#pragma unroll
        for (int off = 32; off > 0; off >>= 1)
            partial += __shfl_down(partial, off, 64);
        if (tid == 0) base_s = partial;
    }
    if (tid < 256) cnt[tid] = 0;
    __syncthreads();

    int total = bucket_cursor[b]; if (total > BCAP) total = BCAP;
    int gbase = base_s;
    const uint32_t* st = staged + (size_t)b * BCAP;

    for (int i = tid; i < total; i += 512) atomicAdd(&cnt[st[i] >> 16], 1);
    __syncthreads();

    int lane = tid & 63, wid = tid >> 6;
    int v = 0, s = 0;
    if (tid < 256) {
        v = cnt[tid]; s = v;
#pragma unroll
        for (int off = 1; off < 64; off <<= 1) {
            int t = __shfl_up(s, off, 64);
            if (lane >= off) s += t;
        }
        if (lane == 63) wt[wid] = s;
    }
    __syncthreads();
    if (tid == 0) { int a = 0; for (int i = 0; i < 4; i++) { int t = wt[i]; wt[i] = a; a += t; } }
    __syncthreads();
    if (tid < 256) {
        int ex = s - v + wt[wid];
        excl[tid] = ex;
        int node = (b << 8) + tid;
        if (node < N_NODES) {
            deg[node]      = v;
            rowstart[node] = gbase + ex;
            inv_deg[node]  = 1.0f / fmaxf((float)v, 1.0f);
        }
    }
    __syncthreads();
    for (int i = tid; i < total; i += 512) {
        uint32_t u = st[i];
        int p = atomicAdd(&excl[u >> 16], 1);
        seg[p] = (int)(u & 0xffffu);
    }
    __syncthreads();
    for (int i = tid; i < total; i += 512)
        csr_col[gbase + i] = (uint16_t)seg[i];
}

// ---------------------------------------------------------------------------
// FUSED agg + layer GEMM. The GEMM for rows [r0,r0+128) needs agg results
// for exactly those nodes -> dependency is block-local. Phase A: each block
// aggregates its 128 nodes' nbr half (r6-frozen gather structure, bit-
// identical epilogue) into an LDS tile (stride 72 -> conflict-free). Phase
// B: GEMM reads self half from global hself, nbr half from LDS. zn is
// double-buffered (reads zn_in, writes zn_out) to avoid cross-block races.
// Saves 2 launches, 2 grid drains, and the 6.4 MB nbr round trip per layer.
// ---------------------------------------------------------------------------
__global__ __launch_bounds__(256, 2) void agg_gemm_kernel(
        const uint16_t* __restrict__ zn_in, const uint16_t* __restrict__ csr_col,
        const int* __restrict__ rowstart, const int* __restrict__ deg,
        const float* __restrict__ inv_deg, const float* __restrict__ bias_nbr,
        const __hip_bfloat16* __restrict__ hself,
        const __hip_bfloat16* __restrict__ wpack_self,
        const __hip_bfloat16* __restrict__ wpack_nbr,
        const float* __restrict__ bias_out,
        __hip_bfloat16* __restrict__ hout, uint16_t* __restrict__ zn_out) {
    __shared__ __align__(16) uint16_t nbr[128 * NB_STRIDE];   // 18432 B
    int wave = threadIdx.x >> 6, lane = threadIdx.x & 63;
    int row0 = blockIdx.x * 128;

    // ---- Phase A: aggregate 128 nodes -> LDS nbr tile ----
    {
        int sub = lane >> 3;               // node slot within wave (0..7)
        int sl  = lane & 7;                // 16 B chunk of the 128 B row
        const uint32_t* zw = (const uint32_t*)zn_in;   // row = 32 dwords
        const float* bb = bias_nbr + sl * 8;
        float4 b0 = *(const float4*)bb;
        float4 b1 = *(const float4*)(bb + 4);

#define ACC8H(U) {                                                      \
    float2 t0 = h2f((U).x); acc[0] += t0.x; acc[1] += t0.y;             \
    float2 t1 = h2f((U).y); acc[2] += t1.x; acc[3] += t1.y;             \
    float2 t2 = h2f((U).z); acc[4] += t2.x; acc[5] += t2.y;             \
    float2 t3 = h2f((U).w); acc[6] += t3.x; acc[7] += t3.y; }

        for (int it = 0; it < 4; it++) {
            int nl   = it * 32 + wave * 8 + sub;       // node_local 0..127
            int node = min(row0 + nl, N_NODES - 1);    // pad rows recompute 49999
            int start = rowstart[node];
            int d     = deg[node];
            float acc[8] = {};
            if (d > 0) {
                int last = start + d - 1;
                int s[8];
#pragma unroll
                for (int k = 0; k < 8; k++) s[k] = csr_col[min(start + k, last)];
                int j = 0;
                for (; j + 8 <= d; j += 8) {
                    int p[8];
#pragma unroll
                    for (int k = 0; k < 8; k++) p[k] = csr_col[min(start + j + 8 + k, last)];
                    uint4 u0 = *(const uint4*)(zw + (size_t)s[0] * 32 + sl * 4);
                    uint4 u1 = *(const uint4*)(zw + (size_t)s[1] * 32 + sl * 4);
                    uint4 u2 = *(const uint4*)(zw + (size_t)s[2] * 32 + sl * 4);
                    uint4 u3 = *(const uint4*)(zw + (size_t)s[3] * 32 + sl * 4);
                    uint4 u4 = *(const uint4*)(zw + (size_t)s[4] * 32 + sl * 4);
                    uint4 u5 = *(const uint4*)(zw + (size_t)s[5] * 32 + sl * 4);
                    uint4 u6 = *(const uint4*)(zw + (size_t)s[6] * 32 + sl * 4);
                    uint4 u7 = *(const uint4*)(zw + (size_t)s[7] * 32 + sl * 4);
                    ACC8H(u0); ACC8H(u1); ACC8H(u2); ACC8H(u3);
                    ACC8H(u4); ACC8H(u5); ACC8H(u6); ACC8H(u7);
#pragma unroll
                    for (int k = 0; k < 8; k++) s[k] = p[k];
                }
                int r = d - j;
#pragma unroll
                for (int k = 0; k < 8; k++) {
                    if (k < r) {
                        uint4 u = *(const uint4*)(zw + (size_t)s[k] * 32 + sl * 4);
                        ACC8H(u);
                    }
                }
            }
            float inv = inv_deg[node];
            uint4 p;
            p.x = (uint32_t)f2bf_bits(fmaxf(acc[0] * inv + b0.x, 0.f))
                | ((uint32_t)f2bf_bits(fmaxf(acc[1] * inv + b0.y, 0.f)) << 16);
            p.y = (uint32_t)f2bf_bits(fmaxf(acc[2] * inv + b0.z, 0.f))
                | ((uint32_t)f2bf_bits(fmaxf(acc[3] * inv + b0.w, 0.f)) << 16);
            p.z = (uint32_t)f2bf_bits(fmaxf(acc[4] * inv + b1.x, 0.f))
                | ((uint32_t)f2bf_bits(fmaxf(acc[5] * inv + b1.y, 0.f)) << 16);
            p.w = (uint32_t)f2bf_bits(fmaxf(acc[6] * inv + b1.z, 0.f))
                | ((uint32_t)f2bf_bits(fmaxf(acc[7] * inv + b1.w, 0.f)) << 16);
            *(uint4*)&nbr[nl * NB_STRIDE + sl * 8] = p;
        }
#undef ACC8H
    }
    __syncthreads();

    // ---- Phase B: GEMM; A-frag ks 0-1 from global self half, ks 2-3 LDS ----
    int lrow = lane & 15, lgrp = lane >> 4;
    int rowb = row0 + wave * 32;
    const __hip_bfloat16* hr0 = hself + (size_t)(rowb + lrow) * D_FEAT + lgrp * 8;
    const __hip_bfloat16* hr1 = hr0 + (size_t)16 * D_FEAT;
    const uint16_t* lr0 = &nbr[(wave * 32 + lrow) * NB_STRIDE + lgrp * 8];
    const uint16_t* lr1 = lr0 + 16 * NB_STRIDE;

    f32x4 accS[2][4] = {};
    f32x4 accN[2][4] = {};
#pragma unroll
    for (int ks = 0; ks < 4; ks++) {
        bf16x8 a0, a1;
        if (ks < 2) {
            a0 = *(const bf16x8*)(hr0 + ks * 32);
            a1 = *(const bf16x8*)(hr1 + ks * 32);
        } else {
            a0 = *(const bf16x8*)(lr0 + (ks - 2) * 32);
            a1 = *(const bf16x8*)(lr1 + (ks - 2) * 32);
        }
#pragma unroll
        for (int ns = 0; ns < 4; ns++) {
            bf16x8 bs = *(const bf16x8*)(wpack_self + ((size_t)(ns * 4 + ks) * 64 + lane) * 8);
            accS[0][ns] = __builtin_amdgcn_mfma_f32_16x16x32_bf16(a0, bs, accS[0][ns], 0, 0, 0);
            accS[1][ns] = __builtin_amdgcn_mfma_f32_16x16x32_bf16(a1, bs, accS[1][ns], 0, 0, 0);
            bf16x8 bn = *(const bf16x8*)(wpack_nbr + ((size_t)(ns * 4 + ks) * 64 + lane) * 8);
            accN[0][ns] = __builtin_amdgcn_mfma_f32_16x16x32_bf16(a0, bn, accN[0][ns], 0, 0, 0);
            accN[1][ns] = __builtin_amdgcn_mfma_f32_16x16x32_bf16(a1, bn, accN[1][ns], 0, 0, 0);
        }
    }
#pragma unroll
    for (int t = 0; t < 2; t++) {
#pragma unroll
        for (int ns = 0; ns < 4; ns++) {
            int colS = ns * 16 + lrow;
            float bvS = bias_out[colS];
#pragma unroll
            for (int i = 0; i < 4; i++) {
                int r = rowb + t * 16 + lgrp * 4 + i;     // < N_PAD, unguarded
                hout[(size_t)r * D_FEAT + colS] =
                    __float2bfloat16(fmaxf(accS[t][ns][i] + bvS, 0.f));
                __half hz = __float2half(accN[t][ns][i]);
                uint16_t hb; __builtin_memcpy(&hb, &hz, 2);
                zn_out[(size_t)r * HALF + colS] = hb;
            }
        }
    }
}

// ---------------------------------------------------------------------------
// Mean aggregation (r6-proven, FROZEN) — standalone for L2 -> MLP.
// ---------------------------------------------------------------------------
__global__ __launch_bounds__(128) void agg8_kernel(
        const uint16_t* __restrict__ zn, const uint16_t* __restrict__ csr_col,
        const int* __restrict__ rowstart, const int* __restrict__ deg,
        const float* __restrict__ inv_deg, const float* __restrict__ bias64,
        __hip_bfloat16* __restrict__ hout) {
    int gid  = blockIdx.x * 128 + threadIdx.x;
    int wnum = gid >> 6;
    int lane = threadIdx.x & 63;
    int sub  = lane >> 3;
    int sl   = lane & 7;
    int node = wnum * 8 + sub;           // grid exact: 6250 waves * 8 = 50000
    int start = rowstart[node];
    int d     = deg[node];
    const uint32_t* zw = (const uint32_t*)zn;
    float acc[8] = {};

#define ACC8H(U) {                                                      \
    float2 t0 = h2f((U).x); acc[0] += t0.x; acc[1] += t0.y;             \
    float2 t1 = h2f((U).y); acc[2] += t1.x; acc[3] += t1.y;             \
    float2 t2 = h2f((U).z); acc[4] += t2.x; acc[5] += t2.y;             \
    float2 t3 = h2f((U).w); acc[6] += t3.x; acc[7] += t3.y; }

    if (d > 0) {
        int last = start + d - 1;
        int s[8];
#pragma unroll
        for (int k = 0; k < 8; k++) s[k] = csr_col[min(start + k, last)];
        int j = 0;
        for (; j + 8 <= d; j += 8) {
            int p[8];
#pragma unroll
            for (int k = 0; k < 8; k++) p[k] = csr_col[min(start + j + 8 + k, last)];
            uint4 u0 = *(const uint4*)(zw + (size_t)s[0] * 32 + sl * 4);
            uint4 u1 = *(const uint4*)(zw + (size_t)s[1] * 32 + sl * 4);
            uint4 u2 = *(const uint4*)(zw + (size_t)s[2] * 32 + sl * 4);
            uint4 u3 = *(const uint4*)(zw + (size_t)s[3] * 32 + sl * 4);
            uint4 u4 = *(const uint4*)(zw + (size_t)s[4] * 32 + sl * 4);
            uint4 u5 = *(const uint4*)(zw + (size_t)s[5] * 32 + sl * 4);
            uint4 u6 = *(const uint4*)(zw + (size_t)s[6] * 32 + sl * 4);
            uint4 u7 = *(const uint4*)(zw + (size_t)s[7] * 32 + sl * 4);
            ACC8H(u0); ACC8H(u1); ACC8H(u2); ACC8H(u3);
            ACC8H(u4); ACC8H(u5); ACC8H(u6); ACC8H(u7);
#pragma unroll
            for (int k = 0; k < 8; k++) s[k] = p[k];
        }
        int r = d - j;
#pragma unroll
        for (int k = 0; k < 8; k++) {
            if (k < r) {
                uint4 u = *(const uint4*)(zw + (size_t)s[k] * 32 + sl * 4);
                ACC8H(u);
            }
        }
    }
#undef ACC8H

    float inv = inv_deg[node];
    const float* bb = bias64 + sl * 8;
    float4 b0 = *(const float4*)bb;
    float4 b1 = *(const float4*)(bb + 4);
    uint4 p;
    p.x = (uint32_t)f2bf_bits(fmaxf(acc[0] * inv + b0.x, 0.f))
        | ((uint32_t)f2bf_bits(fmaxf(acc[1] * inv + b0.y, 0.f)) << 16);
    p.y = (uint32_t)f2bf_bits(fmaxf(acc[2] * inv + b0.z, 0.f))
        | ((uint32_t)f2bf_bits(fmaxf(acc[3] * inv + b0.w, 0.f)) << 16);
    p.z = (uint32_t)f2bf_bits(fmaxf(acc[4] * inv + b1.x, 0.f))
        | ((uint32_t)f2bf_bits(fmaxf(acc[5] * inv + b1.y, 0.f)) << 16);
    p.w = (uint32_t)f2bf_bits(fmaxf(acc[6] * inv + b1.z, 0.f))
        | ((uint32_t)f2bf_bits(fmaxf(acc[7] * inv + b1.w, 0.f)) << 16);
    *(uint4*)((uint32_t*)hout + (size_t)node * 64 + 32 + sl * 4) = p;
}

// ---------------------------------------------------------------------------
// Fused MLP (r6-proven): out[N,40] = relu(h@W1+b1) @ W2 + b2.
// ---------------------------------------------------------------------------
__global__ __launch_bounds__(256, 2) void mlp_fused_kernel(
        const __hip_bfloat16* __restrict__ h, const __hip_bfloat16* __restrict__ w1p,
        const float* __restrict__ b1, const __hip_bfloat16* __restrict__ w2p,
        const float* __restrict__ b2, float* __restrict__ out) {
    __shared__ __align__(16) uint16_t hid[128 * HID_STRIDE];   // 67584 B
    int wave = threadIdx.x >> 6, lane = threadIdx.x & 63;
    int row0 = blockIdx.x * 128 + wave * 32;
    int lrow = lane & 15, lgrp = lane >> 4;

    // ---- Phase 1: hidden = relu(h @ W1 + b1) -> LDS ----
    {
        const __hip_bfloat16* ar0 = h + (size_t)(row0 + lrow) * D_FEAT + lgrp * 8;
        const __hip_bfloat16* ar1 = ar0 + (size_t)16 * D_FEAT;
        f32x4 acc[2][16] = {};
#pragma unroll 1
        for (int ks = 0; ks < 4; ks++) {
            bf16x8 a0 = *(const bf16x8*)(ar0 + ks * 32);
            bf16x8 a1 = *(const bf16x8*)(ar1 + ks * 32);
#pragma unroll
            for (int ns = 0; ns < 16; ns++) {
                bf16x8 bfr = *(const bf16x8*)(w1p + ((size_t)(ns * 4 + ks) * 64 + lane) * 8);
                acc[0][ns] = __builtin_amdgcn_mfma_f32_16x16x32_bf16(a0, bfr, acc[0][ns], 0, 0, 0);
                acc[1][ns] = __builtin_amdgcn_mfma_f32_16x16x32_bf16(a1, bfr, acc[1][ns], 0, 0, 0);
            }
        }
        int lbase = wave * 32;
#pragma unroll
        for (int t = 0; t < 2; t++) {
#pragma unroll
            for (int ns = 0; ns < 16; ns++) {
                int col = ns * 16 + lrow;
                float bv = b1[col];
#pragma unroll
                for (int i = 0; i < 4; i++) {
                    int lr = lbase + t * 16 + lgrp * 4 + i;
                    hid[lr * HID_STRIDE + col] =
                        f2bf_bits(fmaxf(acc[t][ns][i] + bv, 0.f));
                }
            }
        }
    }
    __syncthreads();

    // ---- Phase 2: out = hidden @ W2 + b2 ----
    const uint16_t* br0 = &hid[(wave * 32 + lrow) * HID_STRIDE + lgrp * 8];
    const uint16_t* br1 = br0 + 16 * HID_STRIDE;
    f32x4 acc2[2][3] = {};
#pragma unroll
    for (int ks = 0; ks < 8; ks++) {
        bf16x8 a0 = *(const bf16x8*)(br0 + ks * 32);
        bf16x8 a1 = *(const bf16x8*)(br1 + ks * 32);
#pragma unroll
        for (int ns = 0; ns < 3; ns++) {
            bf16x8 bfr = *(const bf16x8*)(w2p + ((size_t)(ns * 8 + ks) * 64 + lane) * 8);
            acc2[0][ns] = __builtin_amdgcn_mfma_f32_16x16x32_bf16(a0, bfr, acc2[0][ns], 0, 0, 0);
            acc2[1][ns] = __builtin_amdgcn_mfma_f32_16x16x32_bf16(a1, bfr, acc2[1][ns], 0, 0, 0);
        }
    }
#pragma unroll
    for (int t = 0; t < 2; t++) {
#pragma unroll
        for (int ns = 0; ns < 3; ns++) {
            int col = ns * 16 + lrow;
            if (col < LABELS) {
                float bv = b2[col];
#pragma unroll
                for (int i = 0; i < 4; i++) {
                    int r = row0 + t * 16 + lgrp * 4 + i;
                    if (r < N_NODES)                       // d_out: exact size
                        out[(size_t)r * LABELS + col] = acc2[t][ns][i] + bv;
                }
            }
        }
    }
}

// ---------------------------------------------------------------------------
extern "C" void kernel_launch(void* const* d_in, const int* in_sizes, int n_in,
                              void* d_out, int out_size, void* d_ws, size_t ws_size,
                              hipStream_t stream) {
    const float* x      = (const float*)d_in[0];
    const int*   ei     = (const int*)d_in[1];
    const float* selfk  = (const float*)d_in[2];
    const float* nbrk   = (const float*)d_in[3];
    const float* biases = (const float*)d_in[4];
    const float* w1     = (const float*)d_in[5];
    const float* b1     = (const float*)d_in[6];
    const float* w2     = (const float*)d_in[7];
    const float* b2     = (const float*)d_in[8];
    float* out = (float*)d_out;

    const int* row = ei;             // targets
    const int* col = ei + N_EDGES;   // sources

    char* ws = (char*)d_ws;
    size_t off = 0;
    auto alloc = [&](size_t bytes) -> char* {
        char* p = ws + off;
        off = (off + bytes + 255) & ~(size_t)255;
        return p;
    };
    int*   deg       = (int*)  alloc((size_t)N_NODES * 4);
    int*   rowstart  = (int*)  alloc((size_t)N_NODES * 4);
    float* inv_deg   = (float*)alloc((size_t)N_NODES * 4);
    int*   bucket_cursor = (int*)alloc(256 * 4);
    uint16_t* csr_col = (uint16_t*)alloc((size_t)N_EDGES * 2);
    uint32_t* staged = (uint32_t*)alloc((size_t)NBUCK * BCAP * 4);
    __hip_bfloat16* wpack  = (__hip_bfloat16*)alloc(PK_TOTAL * 2);
    __hip_bfloat16* hA     = (__hip_bfloat16*)alloc((size_t)N_PAD * D_FEAT * 2);
    __hip_bfloat16* hB     = (__hip_bfloat16*)alloc((size_t)N_PAD * D_FEAT * 2);
    uint16_t*       znA    = (uint16_t*)alloc((size_t)N_PAD * HALF * 2);
    uint16_t*       znB    = (uint16_t*)alloc((size_t)N_PAD * HALF * 2);

    hipMemsetAsync(bucket_cursor, 0, 256 * 4, stream);

    // scatter (196 blocks) + weight pack (32 blocks), one launch
    scatter_pack_kernel<<<228, 1024, 0, stream>>>(row, col, bucket_cursor, staged,
                                                  selfk, nbrk, w1, w2, wpack);

    const int layer_blocks = N_PAD / 128;                  // 392
    const int agg_blocks   = N_NODES / 16;                 // 3125

    // L0 GEMM fused with CSR fill:
    gemm0_fill_kernel<<<392, 512, 0, stream>>>(
        x, wpack + PK_SELF(0), wpack + PK_NBR(0), biases, hA, znA,
        staged, bucket_cursor, deg, rowstart, inv_deg, csr_col);

    // L1: agg(znA) + GEMM fused; reads hA self half, writes hB self + znB
    agg_gemm_kernel<<<layer_blocks, 256, 0, stream>>>(
        znA, csr_col, rowstart, deg, inv_deg, biases + 64,
        hA, wpack + PK_SELF(1), wpack + PK_NBR(1), biases + 128, hB, znB);

    // L2: agg(znB) + GEMM fused; reads hB self half, writes hA self + znA
    agg_gemm_kernel<<<layer_blocks, 256, 0, stream>>>(
        znB, csr_col, rowstart, deg, inv_deg, biases + 128 + 64,
        hB, wpack + PK_SELF(2), wpack + PK_NBR(2), biases + 256, hA, znA);

    // finish L2's h: aggregate znA -> hA nbr cols (global), then MLP
    agg8_kernel<<<agg_blocks, 128, 0, stream>>>(znA, csr_col, rowstart, deg,
                                                inv_deg, biases + 256 + 64, hA);

    mlp_fused_kernel<<<layer_blocks, 256, 0, stream>>>(hA, wpack + PK_W1, b1,
                                                       wpack + PK_W2, b2, out);
}

// Round 12
// 197.516 us; speedup vs baseline: 1.0341x; 1.0341x over previous
//
#include <hip/hip_runtime.h>
#include <hip/hip_bf16.h>
#include <hip/hip_fp16.h>
#include <cstdint>
#include <cstddef>

#define N_NODES 50000
#define N_PAD   50176    // padded rows for guard-free GEMM tiles
#define N_EDGES 800000
#define D_FEAT  128
#define HALF    64
#define HIDDEN  256
#define LABELS  40

#define NBUCK 196        // ceil(50000/256) buckets of 256 nodes (node>>8)
#define BCAP  5632       // staging cap per bucket; E[cnt]=4096, sigma~64 (24 sigma)
#define EDGES_PER_BLK 4096

#define HID_STRIDE 264   // LDS hidden-tile row stride (bf16)

typedef __attribute__((ext_vector_type(8))) short bf16x8;
typedef __attribute__((ext_vector_type(4))) float f32x4;

// Packed-weight layout offsets (in bf16 elements).
#define PK_SELF(L) ((size_t)(L) * 8192)
#define PK_NBR(L)  (24576 + (size_t)(L) * 8192)
#define PK_W1      49152
#define PK_W2      81920
#define PK_TOTAL   94208

__device__ inline uint16_t f2bf_bits(float f) {
    __hip_bfloat16 b = __float2bfloat16(f);
    uint16_t u; __builtin_memcpy(&u, &b, 2); return u;
}

__device__ inline float2 h2f(uint32_t u) {
    __half2 h; __builtin_memcpy(&h, &u, 4);
    return __half22float2(h);
}

// ---------------------------------------------------------------------------
// CSR build phase 1: bucket scatter. 196 blocks x 4096 edges. (r6-proven)
// ---------------------------------------------------------------------------
__global__ __launch_bounds__(1024) void bucket_scatter_kernel(
        const int* __restrict__ row, const int* __restrict__ col,
        int* __restrict__ bucket_cursor, uint32_t* __restrict__ staged) {
    __shared__ int hist[NBUCK];
    __shared__ int hbase[NBUCK];
    int tid  = threadIdx.x;
    int e0   = blockIdx.x * EDGES_PER_BLK;
    int eend = e0 + EDGES_PER_BLK; if (eend > N_EDGES) eend = N_EDGES;

    for (int i = tid; i < NBUCK; i += 1024) hist[i] = 0;
    __syncthreads();

    int rr[4], cc[4]; int ne = 0;
    for (int e = e0 + tid; e < eend; e += 1024) {
        rr[ne] = row[e]; cc[ne] = col[e]; ne++;
    }
    for (int i = 0; i < ne; i++) atomicAdd(&hist[rr[i] >> 8], 1);
    __syncthreads();

    for (int i = tid; i < NBUCK; i += 1024) {
        hbase[i] = atomicAdd(&bucket_cursor[i], hist[i]);
        hist[i]  = 0;
    }
    __syncthreads();

    for (int i = 0; i < ne; i++) {
        int b   = rr[i] >> 8;
        int off = atomicAdd(&hist[b], 1);
        int pos = hbase[b] + off;
        if (pos < BCAP)
            staged[(size_t)b * BCAP + pos] =
                ((uint32_t)(rr[i] & 255) << 16) | (uint32_t)cc[i];
    }
}

// ---------------------------------------------------------------------------
// Pack all weights to bf16 in MFMA B-fragment order. (r6-proven)
// ---------------------------------------------------------------------------
__global__ __launch_bounds__(256) void pack_all_kernel(
        const float* __restrict__ selfk, const float* __restrict__ nbrk,
        const float* __restrict__ w1, const float* __restrict__ w2,
        __hip_bfloat16* __restrict__ wpack) {
    int m = blockIdx.y;
    const float* W; int K, Ncols, Npad; size_t dstoff;
    if (m < 3)      { W = selfk + (size_t)m*D_FEAT*HALF;      K=128; Ncols=64;  Npad=64;  dstoff = PK_SELF(m); }
    else if (m < 6) { W = nbrk  + (size_t)(m-3)*D_FEAT*HALF;  K=128; Ncols=64;  Npad=64;  dstoff = PK_NBR(m-3); }
    else if (m == 6){ W = w1;                                 K=128; Ncols=256; Npad=256; dstoff = PK_W1; }
    else            { W = w2;                                 K=256; Ncols=40;  Npad=48;  dstoff = PK_W2; }
    int ksteps = K / 32;
    int total  = ksteps * (Npad / 16) * 64;
    int t = blockIdx.x * blockDim.x + threadIdx.x;
    if (t >= total) return;
    int lane = t & 63;
    int rest = t >> 6;
    int ks   = rest % ksteps;
    int ns   = rest / ksteps;
    int colb = ns * 16 + (lane & 15);
    int kb   = ks * 32 + (lane >> 4) * 8;
    __hip_bfloat16* dst = wpack + dstoff + (size_t)t * 8;
#pragma unroll
    for (int j = 0; j < 8; j++) {
        float v = (colb < Ncols) ? W[(size_t)(kb + j) * Ncols + colb] : 0.f;
        dst[j] = __float2bfloat16(v);
    }
}

// ---------------------------------------------------------------------------
// GEMM body (r6-proven arithmetic), parameterized by wave-count: each wave
// handles 32 rows; caller passes row0 for this wave.
// ---------------------------------------------------------------------------
template<bool AF32>
__device__ inline void gemm_wave_body(
        const void* __restrict__ Ain, int row0, int lane,
        const __hip_bfloat16* __restrict__ wpack_self,
        const __hip_bfloat16* __restrict__ wpack_nbr,
        const float* __restrict__ bias,
        __hip_bfloat16* __restrict__ hout, uint16_t* __restrict__ zn) {
    int lrow = lane & 15, lgrp = lane >> 4;

    const __hip_bfloat16 *hr0 = nullptr, *hr1 = nullptr;
    const float *xr0 = nullptr, *xr1 = nullptr;
    if constexpr (AF32) {
        const float* x = (const float*)Ain;
        int r0 = min(row0 + lrow, N_NODES - 1);        // clamp: x has exactly N_NODES rows
        int r1 = min(row0 + lrow + 16, N_NODES - 1);
        xr0 = x + (size_t)r0 * D_FEAT + lgrp * 8;
        xr1 = x + (size_t)r1 * D_FEAT + lgrp * 8;
    } else {
        const __hip_bfloat16* h = (const __hip_bfloat16*)Ain;
        hr0 = h + (size_t)(row0 + lrow) * D_FEAT + lgrp * 8;
        hr1 = hr0 + (size_t)16 * D_FEAT;
    }

    f32x4 accS[2][4] = {};
    f32x4 accN[2][4] = {};
#pragma unroll
    for (int ks = 0; ks < 4; ks++) {
        bf16x8 a0, a1;
        if constexpr (AF32) {
            float4 u0  = *(const float4*)(xr0 + ks * 32);
            float4 u0b = *(const float4*)(xr0 + ks * 32 + 4);
            float4 u1  = *(const float4*)(xr1 + ks * 32);
            float4 u1b = *(const float4*)(xr1 + ks * 32 + 4);
            float f0[8] = {u0.x, u0.y, u0.z, u0.w, u0b.x, u0b.y, u0b.z, u0b.w};
            float f1[8] = {u1.x, u1.y, u1.z, u1.w, u1b.x, u1b.y, u1b.z, u1b.w};
#pragma unroll
            for (int j = 0; j < 8; j++) { a0[j] = (short)f2bf_bits(f0[j]); a1[j] = (short)f2bf_bits(f1[j]); }
        } else {
            a0 = *(const bf16x8*)(hr0 + ks * 32);
            a1 = *(const bf16x8*)(hr1 + ks * 32);
        }
#pragma unroll
        for (int ns = 0; ns < 4; ns++) {
            bf16x8 bs = *(const bf16x8*)(wpack_self + ((size_t)(ns * 4 + ks) * 64 + lane) * 8);
            accS[0][ns] = __builtin_amdgcn_mfma_f32_16x16x32_bf16(a0, bs, accS[0][ns], 0, 0, 0);
            accS[1][ns] = __builtin_amdgcn_mfma_f32_16x16x32_bf16(a1, bs, accS[1][ns], 0, 0, 0);
            bf16x8 bn = *(const bf16x8*)(wpack_nbr + ((size_t)(ns * 4 + ks) * 64 + lane) * 8);
            accN[0][ns] = __builtin_amdgcn_mfma_f32_16x16x32_bf16(a0, bn, accN[0][ns], 0, 0, 0);
            accN[1][ns] = __builtin_amdgcn_mfma_f32_16x16x32_bf16(a1, bn, accN[1][ns], 0, 0, 0);
        }
    }
#pragma unroll
    for (int t = 0; t < 2; t++) {
#pragma unroll
        for (int ns = 0; ns < 4; ns++) {
            int colS = ns * 16 + lrow;
            float bvS = bias[colS];
#pragma unroll
            for (int i = 0; i < 4; i++) {
                int r = row0 + t * 16 + lgrp * 4 + i;     // < N_PAD, unguarded
                hout[(size_t)r * D_FEAT + colS] =
                    __float2bfloat16(fmaxf(accS[t][ns][i] + bvS, 0.f));
                __half hz = __float2half(accN[t][ns][i]);
                uint16_t hb; __builtin_memcpy(&hb, &hz, 2);
                zn[(size_t)r * HALF + colS] = hb;
            }
        }
    }
}

// ---------------------------------------------------------------------------
// Standalone layer GEMM (L1/L2): 256 threads, 128 rows/block. (r6-proven)
// ---------------------------------------------------------------------------
__global__ __launch_bounds__(256, 2) void layer_gemm_kernel(
        const void* __restrict__ Ain,
        const __hip_bfloat16* __restrict__ wpack_self,
        const __hip_bfloat16* __restrict__ wpack_nbr,
        const float* __restrict__ bias,
        __hip_bfloat16* __restrict__ hout, uint16_t* __restrict__ zn) {
    int wave = threadIdx.x >> 6, lane = threadIdx.x & 63;
    int row0 = blockIdx.x * 128 + wave * 32;
    gemm_wave_body<false>(Ain, row0, lane, wpack_self, wpack_nbr, bias, hout, zn);
}

// ---------------------------------------------------------------------------
// FUSED: L0 GEMM + CSR bucket_fill in ONE launch (they are independent:
// gemm0 needs only x+weights; fill needs only staged/cursor from scatter).
// 392 blocks x 512 threads: blocks [0,196) = gemm (8 waves x 32 rows = 256
// rows/block), blocks [196,392) = fill (same algorithm as r6 at stride 512).
// Fill hides under the GEMM's shadow -> saves its serial ~8-12 us. (r10 WIN)
// ---------------------------------------------------------------------------
__global__ __launch_bounds__(512, 2) void gemm0_fill_kernel(
        const float* __restrict__ x,
        const __hip_bfloat16* __restrict__ wpack_self,
        const __hip_bfloat16* __restrict__ wpack_nbr,
        const float* __restrict__ bias,
        __hip_bfloat16* __restrict__ hout, uint16_t* __restrict__ zn,
        const uint32_t* __restrict__ staged, const int* __restrict__ bucket_cursor,
        int* __restrict__ deg, int* __restrict__ rowstart,
        float* __restrict__ inv_deg, uint16_t* __restrict__ csr_col) {
    __shared__ int cnt[256];
    __shared__ int excl[256];
    __shared__ int wt[4];
    __shared__ int seg[BCAP];
    __shared__ int base_s;

    if (blockIdx.x < 196) {
        // ---- L0 GEMM: 256 rows/block ----
        int wave = threadIdx.x >> 6, lane = threadIdx.x & 63;
        int row0 = blockIdx.x * 256 + wave * 32;
        gemm_wave_body<true>((const void*)x, row0, lane,
                             wpack_self, wpack_nbr, bias, hout, zn);
        return;
    }

    // ---- bucket_fill (r6 algorithm, 512 threads) ----
    int b   = blockIdx.x - 196;
    int tid = threadIdx.x;

    if (tid < 64) {                      // wave 0: gbase = sum cursor[i<b]
        int partial = 0;
        for (int i = tid; i < b; i += 64) partial += bucket_cursor[i];
#pragma unroll
        for (int off = 32; off > 0; off >>= 1)
            partial += __shfl_down(partial, off, 64);
        if (tid == 0) base_s = partial;
    }
    if (tid < 256) cnt[tid] = 0;
    __syncthreads();

    int total = bucket_cursor[b]; if (total > BCAP) total = BCAP;
    int gbase = base_s;
    const uint32_t* st = staged + (size_t)b * BCAP;

    for (int i = tid; i < total; i += 512) atomicAdd(&cnt[st[i] >> 16], 1);
    __syncthreads();

    int lane = tid & 63, wid = tid >> 6;
    int v = 0, s = 0;
    if (tid < 256) {
        v = cnt[tid]; s = v;
#pragma unroll
        for (int off = 1; off < 64; off <<= 1) {
            int t = __shfl_up(s, off, 64);
            if (lane >= off) s += t;
        }
        if (lane == 63) wt[wid] = s;
    }
    __syncthreads();
    if (tid == 0) { int a = 0; for (int i = 0; i < 4; i++) { int t = wt[i]; wt[i] = a; a += t; } }
    __syncthreads();
    if (tid < 256) {
        int ex = s - v + wt[wid];
        excl[tid] = ex;
        int node = (b << 8) + tid;
        if (node < N_NODES) {
            deg[node]      = v;
            rowstart[node] = gbase + ex;
            inv_deg[node]  = 1.0f / fmaxf((float)v, 1.0f);
        }
    }
    __syncthreads();
    for (int i = tid; i < total; i += 512) {
        uint32_t u = st[i];
        int p = atomicAdd(&excl[u >> 16], 1);
        seg[p] = (int)(u & 0xffffu);
    }
    __syncthreads();
    for (int i = tid; i < total; i += 512)
        csr_col[gbase + i] = (uint16_t)seg[i];
}

// ---------------------------------------------------------------------------
// Mean aggregation (r6-proven, FROZEN): 8 nodes/wave, 8 lanes/node, 8
// independent full-line gathers in flight + 8-ahead clamped index prefetch.
// ---------------------------------------------------------------------------
__global__ __launch_bounds__(128) void agg8_kernel(
        const uint16_t* __restrict__ zn, const uint16_t* __restrict__ csr_col,
        const int* __restrict__ rowstart, const int* __restrict__ deg,
        const float* __restrict__ inv_deg, const float* __restrict__ bias64,
        __hip_bfloat16* __restrict__ hout) {
    int gid  = blockIdx.x * 128 + threadIdx.x;
    int wnum = gid >> 6;
    int lane = threadIdx.x & 63;
    int sub  = lane >> 3;                // node slot within wave (0..7)
    int sl   = lane & 7;                 // covers dwords [4*sl, 4*sl+3] of the 32-dword row
    int node = wnum * 8 + sub;           // grid exact: 6250 waves * 8 = 50000
    int start = rowstart[node];
    int d     = deg[node];
    const uint32_t* zw = (const uint32_t*)zn;   // row = 32 dwords (64 fp16)
    float acc[8] = {};

#define ACC8H(U) {                                                      \
    float2 t0 = h2f((U).x); acc[0] += t0.x; acc[1] += t0.y;             \
    float2 t1 = h2f((U).y); acc[2] += t1.x; acc[3] += t1.y;             \
    float2 t2 = h2f((U).z); acc[4] += t2.x; acc[5] += t2.y;             \
    float2 t3 = h2f((U).w); acc[6] += t3.x; acc[7] += t3.y; }

    if (d > 0) {
        int last = start + d - 1;
        int s[8];
#pragma unroll
        for (int k = 0; k < 8; k++) s[k] = csr_col[min(start + k, last)];
        int j = 0;
        for (; j + 8 <= d; j += 8) {
            int p[8];
#pragma unroll
            for (int k = 0; k < 8; k++) p[k] = csr_col[min(start + j + 8 + k, last)];
            uint4 u0 = *(const uint4*)(zw + (size_t)s[0] * 32 + sl * 4);
            uint4 u1 = *(const uint4*)(zw + (size_t)s[1] * 32 + sl * 4);
            uint4 u2 = *(const uint4*)(zw + (size_t)s[2] * 32 + sl * 4);
            uint4 u3 = *(const uint4*)(zw + (size_t)s[3] * 32 + sl * 4);
            uint4 u4 = *(const uint4*)(zw + (size_t)s[4] * 32 + sl * 4);
            uint4 u5 = *(const uint4*)(zw + (size_t)s[5] * 32 + sl * 4);
            uint4 u6 = *(const uint4*)(zw + (size_t)s[6] * 32 + sl * 4);
            uint4 u7 = *(const uint4*)(zw + (size_t)s[7] * 32 + sl * 4);
            ACC8H(u0); ACC8H(u1); ACC8H(u2); ACC8H(u3);
            ACC8H(u4); ACC8H(u5); ACC8H(u6); ACC8H(u7);
#pragma unroll
            for (int k = 0; k < 8; k++) s[k] = p[k];
        }
        int r = d - j;
#pragma unroll
        for (int k = 0; k < 8; k++) {
            if (k < r) {
                uint4 u = *(const uint4*)(zw + (size_t)s[k] * 32 + sl * 4);
                ACC8H(u);
            }
        }
    }
#undef ACC8H

    float inv = inv_deg[node];
    const float* bb = bias64 + sl * 8;
    float4 b0 = *(const float4*)bb;
    float4 b1 = *(const float4*)(bb + 4);
    uint4 p;
    p.x = (uint32_t)f2bf_bits(fmaxf(acc[0] * inv + b0.x, 0.f))
        | ((uint32_t)f2bf_bits(fmaxf(acc[1] * inv + b0.y, 0.f)) << 16);
    p.y = (uint32_t)f2bf_bits(fmaxf(acc[2] * inv + b0.z, 0.f))
        | ((uint32_t)f2bf_bits(fmaxf(acc[3] * inv + b0.w, 0.f)) << 16);
    p.z = (uint32_t)f2bf_bits(fmaxf(acc[4] * inv + b1.x, 0.f))
        | ((uint32_t)f2bf_bits(fmaxf(acc[5] * inv + b1.y, 0.f)) << 16);
    p.w = (uint32_t)f2bf_bits(fmaxf(acc[6] * inv + b1.z, 0.f))
        | ((uint32_t)f2bf_bits(fmaxf(acc[7] * inv + b1.w, 0.f)) << 16);
    // nbr half of the 256B row starts at dword 32
    *(uint4*)((uint32_t*)hout + (size_t)node * 64 + 32 + sl * 4) = p;
}

// ---------------------------------------------------------------------------
// Fused MLP (r6-proven): out[N,40] = relu(h@W1+b1) @ W2 + b2.
// ---------------------------------------------------------------------------
__global__ __launch_bounds__(256, 2) void mlp_fused_kernel(
        const __hip_bfloat16* __restrict__ h, const __hip_bfloat16* __restrict__ w1p,
        const float* __restrict__ b1, const __hip_bfloat16* __restrict__ w2p,
        const float* __restrict__ b2, float* __restrict__ out) {
    __shared__ __align__(16) uint16_t hid[128 * HID_STRIDE];   // 67584 B
    int wave = threadIdx.x >> 6, lane = threadIdx.x & 63;
    int row0 = blockIdx.x * 128 + wave * 32;
    int lrow = lane & 15, lgrp = lane >> 4;

    // ---- Phase 1: hidden = relu(h @ W1 + b1) -> LDS ----
    {
        const __hip_bfloat16* ar0 = h + (size_t)(row0 + lrow) * D_FEAT + lgrp * 8;
        const __hip_bfloat16* ar1 = ar0 + (size_t)16 * D_FEAT;
        f32x4 acc[2][16] = {};
#pragma unroll 1
        for (int ks = 0; ks < 4; ks++) {
            bf16x8 a0 = *(const bf16x8*)(ar0 + ks * 32);
            bf16x8 a1 = *(const bf16x8*)(ar1 + ks * 32);
#pragma unroll
            for (int ns = 0; ns < 16; ns++) {
                bf16x8 bfr = *(const bf16x8*)(w1p + ((size_t)(ns * 4 + ks) * 64 + lane) * 8);
                acc[0][ns] = __builtin_amdgcn_mfma_f32_16x16x32_bf16(a0, bfr, acc[0][ns], 0, 0, 0);
                acc[1][ns] = __builtin_amdgcn_mfma_f32_16x16x32_bf16(a1, bfr, acc[1][ns], 0, 0, 0);
            }
        }
        int lbase = wave * 32;
#pragma unroll
        for (int t = 0; t < 2; t++) {
#pragma unroll
            for (int ns = 0; ns < 16; ns++) {
                int col = ns * 16 + lrow;
                float bv = b1[col];
#pragma unroll
                for (int i = 0; i < 4; i++) {
                    int lr = lbase + t * 16 + lgrp * 4 + i;
                    hid[lr * HID_STRIDE + col] =
                        f2bf_bits(fmaxf(acc[t][ns][i] + bv, 0.f));
                }
            }
        }
    }
    __syncthreads();

    // ---- Phase 2: out = hidden @ W2 + b2 ----
    const uint16_t* br0 = &hid[(wave * 32 + lrow) * HID_STRIDE + lgrp * 8];
    const uint16_t* br1 = br0 + 16 * HID_STRIDE;
    f32x4 acc2[2][3] = {};
#pragma unroll
    for (int ks = 0; ks < 8; ks++) {
        bf16x8 a0 = *(const bf16x8*)(br0 + ks * 32);
        bf16x8 a1 = *(const bf16x8*)(br1 + ks * 32);
#pragma unroll
        for (int ns = 0; ns < 3; ns++) {
            bf16x8 bfr = *(const bf16x8*)(w2p + ((size_t)(ns * 8 + ks) * 64 + lane) * 8);
            acc2[0][ns] = __builtin_amdgcn_mfma_f32_16x16x32_bf16(a0, bfr, acc2[0][ns], 0, 0, 0);
            acc2[1][ns] = __builtin_amdgcn_mfma_f32_16x16x32_bf16(a1, bfr, acc2[1][ns], 0, 0, 0);
        }
    }
#pragma unroll
    for (int t = 0; t < 2; t++) {
#pragma unroll
        for (int ns = 0; ns < 3; ns++) {
            int col = ns * 16 + lrow;
            if (col < LABELS) {
                float bv = b2[col];
#pragma unroll
                for (int i = 0; i < 4; i++) {
                    int r = row0 + t * 16 + lgrp * 4 + i;
                    if (r < N_NODES)                       // d_out: exact size
                        out[(size_t)r * LABELS + col] = acc2[t][ns][i] + bv;
                }
            }
        }
    }
}

// ---------------------------------------------------------------------------
extern "C" void kernel_launch(void* const* d_in, const int* in_sizes, int n_in,
                              void* d_out, int out_size, void* d_ws, size_t ws_size,
                              hipStream_t stream) {
    const float* x      = (const float*)d_in[0];
    const int*   ei     = (const int*)d_in[1];
    const float* selfk  = (const float*)d_in[2];
    const float* nbrk   = (const float*)d_in[3];
    const float* biases = (const float*)d_in[4];
    const float* w1     = (const float*)d_in[5];
    const float* b1     = (const float*)d_in[6];
    const float* w2     = (const float*)d_in[7];
    const float* b2     = (const float*)d_in[8];
    float* out = (float*)d_out;

    const int* row = ei;             // targets
    const int* col = ei + N_EDGES;   // sources

    char* ws = (char*)d_ws;
    size_t off = 0;
    auto alloc = [&](size_t bytes) -> char* {
        char* p = ws + off;
        off = (off + bytes + 255) & ~(size_t)255;
        return p;
    };
    int*   deg       = (int*)  alloc((size_t)N_NODES * 4);
    int*   rowstart  = (int*)  alloc((size_t)N_NODES * 4);
    float* inv_deg   = (float*)alloc((size_t)N_NODES * 4);
    int*   bucket_cursor = (int*)alloc(256 * 4);
    uint16_t* csr_col = (uint16_t*)alloc((size_t)N_EDGES * 2);
    uint32_t* staged = (uint32_t*)alloc((size_t)NBUCK * BCAP * 4);
    __hip_bfloat16* wpack  = (__hip_bfloat16*)alloc(PK_TOTAL * 2);
    __hip_bfloat16* hA     = (__hip_bfloat16*)alloc((size_t)N_PAD * D_FEAT * 2);
    __hip_bfloat16* hB     = (__hip_bfloat16*)alloc((size_t)N_PAD * D_FEAT * 2);
    uint16_t*       zn     = (uint16_t*)alloc((size_t)N_PAD * HALF * 2);

    hipMemsetAsync(bucket_cursor, 0, 256 * 4, stream);

    const int scat_blocks = (N_EDGES + EDGES_PER_BLK - 1) / EDGES_PER_BLK;  // 196
    bucket_scatter_kernel<<<scat_blocks, 1024, 0, stream>>>(row, col, bucket_cursor, staged);

    dim3 pgrid(16, 8);
    pack_all_kernel<<<pgrid, 256, 0, stream>>>(selfk, nbrk, w1, w2, wpack);

    const int layer_blocks = N_PAD / 128;                  // 392
    const int agg_blocks   = N_NODES / 16;                 // 3125: 8 nodes/wave, 2 waves/block

    // L0 GEMM fused with CSR fill (independent work, one launch):
    gemm0_fill_kernel<<<392, 512, 0, stream>>>(
        x, wpack + PK_SELF(0), wpack + PK_NBR(0), biases, hA, zn,
        staged, bucket_cursor, deg, rowstart, inv_deg, csr_col);
    agg8_kernel<<<agg_blocks, 128, 0, stream>>>(zn, csr_col, rowstart, deg,
                                                inv_deg, biases + 64, hA);
    // L1
    layer_gemm_kernel<<<layer_blocks, 256, 0, stream>>>(
        (const void*)hA, wpack + PK_SELF(1), wpack + PK_NBR(1), biases + 128, hB, zn);
    agg8_kernel<<<agg_blocks, 128, 0, stream>>>(zn, csr_col, rowstart, deg,
                                                inv_deg, biases + 128 + 64, hB);
    // L2
    layer_gemm_kernel<<<layer_blocks, 256, 0, stream>>>(
        (const void*)hB, wpack + PK_SELF(2), wpack + PK_NBR(2), biases + 256, hA, zn);
    agg8_kernel<<<agg_blocks, 128, 0, stream>>>(zn, csr_col, rowstart, deg,
                                                inv_deg, biases + 256 + 64, hA);

    mlp_fused_kernel<<<layer_blocks, 256, 0, stream>>>(hA, wpack + PK_W1, b1,
                                                       wpack + PK_W2, b2, out);
}